// Round 19
// baseline (58.449 us; speedup 1.0000x reference)
//
#include <hip/hip_runtime.h>

#define KS    13
#define HALF  6
#define TY    32              // output rows per strip (R13 geometry — best measured)
#define NITER (TY + 12)       // 44 staged rows
#define NK    (NITER / 2)     // 22 iterations, 2 rows per barrier
#define IMG_H 1024
#define IMG_W 1024

#define GLOBAL_AS __attribute__((address_space(1)))
#define LDS_AS    __attribute__((address_space(3)))

typedef float vfloat4 __attribute__((ext_vector_type(4)));  // native vec for nt-store

__device__ __forceinline__ int reflect_idx(int i, int n) {
    if (i < 0) i = -i;
    if (i >= n) i = 2 * n - 2 - i;
    return i;
}

struct Ctx {
    const float* xin;
    float*       o;
    float        g[KS];
    int          t;        // thread's column granule: cols 4t..4t+3
    int          r0;       // strip's first output row
    bool         interior; // 2 <= t <= 253 : LDS window read needs no column reflect
};

// Stage rows 2k,2k+1 into LDS pair (k&1) via global_load_lds width-16:
// HBM -> LDS direct, no VGPR round-trip, no ds_write. LDS dest is
// wave-uniform base (granule 64w) + lane*16 -- exactly our linear layout.
__device__ __forceinline__ void stage2(const Ctx& cx, float (*s)[IMG_W], int k) {
    const int bp = (k & 1) * 2;
    const int ra = reflect_idx(cx.r0 + 2 * k - 6, IMG_H);
    const int rb = reflect_idx(cx.r0 + 2 * k - 5, IMG_H);
    const float* pa = cx.xin + (size_t)ra * IMG_W + 4 * cx.t;
    const float* pb = cx.xin + (size_t)rb * IMG_W + 4 * cx.t;
    float* la = &s[bp + 0][4 * (cx.t & ~63)];   // wave-uniform
    float* lb = &s[bp + 1][4 * (cx.t & ~63)];
    __builtin_amdgcn_global_load_lds((const GLOBAL_AS void*)pa, (LDS_AS void*)la, 16, 0, 0);
    __builtin_amdgcn_global_load_lds((const GLOBAL_AS void*)pb, (LDS_AS void*)lb, 16, 0, 0);
}

// H-filter one staged row from LDS: 20-float window -> 4 outputs.
__device__ __forceinline__ float4 h_filter(const float* srow, const Ctx& cx) {
    float f[20];
    if (cx.interior) {
        #pragma unroll
        for (int k = 0; k < 5; ++k) {
            float4 v = *reinterpret_cast<const float4*>(srow + 4 * cx.t - 8 + 4 * k);
            f[4*k+0] = v.x; f[4*k+1] = v.y; f[4*k+2] = v.z; f[4*k+3] = v.w;
        }
    } else {
        #pragma unroll
        for (int k = 0; k < 20; ++k)
            f[k] = srow[reflect_idx(4 * cx.t - 8 + k, IMG_W)];
    }
    float4 h = make_float4(0.f, 0.f, 0.f, 0.f);
    #pragma unroll
    for (int j = 0; j < KS; ++j) {
        h.x += cx.g[j] * f[2 + j];
        h.y += cx.g[j] * f[3 + j];
        h.z += cx.g[j] * f[4 + j];
        h.w += cx.g[j] * f[5 + j];
    }
    return h;
}

__device__ __forceinline__ void nt_store4(float* p, const float4& a) {
    vfloat4 v = { a.x, a.y, a.z, a.w };
    __builtin_nontemporal_store(v, reinterpret_cast<vfloat4*>(p));
}

// Iteration k (= outer*7 + U): (1) issue gload_lds for rows 2k+2,2k+3 into the
// opposite pair; (2) H-filter rows 2k,2k+1 from pair k&1 into window slots
// (2U)%14,(2U+1)%14; (3) V-filter -> output rows r0+2k-12, r0+2k-11 (nt store);
// (4) __syncthreads -- its vmcnt(0) drain is harmless: the gload_lds had the
// whole compute phase in flight. WAR safety: pair k&1 reads complete (use-waits)
// before barrier k; iter k+1's gload_lds into pair k&1 issue after barrier k.
template<int U>
__device__ __forceinline__ void body2(int outer, const Ctx& cx, float (*s)[IMG_W],
                                      float4 (&w)[14])
{
    const int k = outer * 7 + U;
    if (k >= NK) return;                 // block-uniform guard (barrier-safe)
    const int n0 = 2 * k;
    const int bp = (k & 1) * 2;

    if (k + 1 < NK) stage2(cx, s, k + 1);

    // two H-filters into the rolling 14-slot window
    w[(2 * U) % 14]     = h_filter(s[bp + 0], cx);
    w[(2 * U + 1) % 14] = h_filter(s[bp + 1], cx);

    // two V-filters -> output rows r0+n0-12, r0+n0-11
    if (n0 >= 12) {
        float4 a0 = make_float4(0.f, 0.f, 0.f, 0.f);
        float4 a1 = make_float4(0.f, 0.f, 0.f, 0.f);
        #pragma unroll
        for (int j = 0; j < KS; ++j) {
            const float4 v0 = w[(2 * U + 2 + j) % 14];
            const float4 v1 = w[(2 * U + 3 + j) % 14];
            a0.x += cx.g[j] * v0.x;  a1.x += cx.g[j] * v1.x;
            a0.y += cx.g[j] * v0.y;  a1.y += cx.g[j] * v1.y;
            a0.z += cx.g[j] * v0.z;  a1.z += cx.g[j] * v1.z;
            a0.w += cx.g[j] * v0.w;  a1.w += cx.g[j] * v1.w;
        }
        // nontemporal: output is never re-read; don't evict L3-resident input
        nt_store4(cx.o + (size_t)(cx.r0 + n0 - 12) * IMG_W + 4 * cx.t, a0);
        nt_store4(cx.o + (size_t)(cx.r0 + n0 - 11) * IMG_W + 4 * cx.t, a1);
    }

    if (k + 1 < NK) __syncthreads();
}

// No launch-bounds min-waves (R2: VGPR cap -> spill). Expect ~90 VGPR.
__global__ __launch_bounds__(256) void gauss_blur_stream(
    const float* __restrict__ x, const float* __restrict__ k2d,
    float* __restrict__ out)
{
    __shared__ float s[4][IMG_W];   // 16384 B: two ping-pong row PAIRS

    Ctx cx;
    cx.t  = threadIdx.x;
    cx.r0 = blockIdx.x * TY;
    const int img = blockIdx.y;
    cx.xin = x + (size_t)img * IMG_H * IMG_W;
    cx.o   = out + (size_t)img * IMG_H * IMG_W;
    cx.interior = (cx.t >= 2) && (cx.t <= 253);

    // 1D taps: k2d = outer(g,g) exactly, g[i] = k2d[i][6]/sqrt(k2d[6][6])
    {
        float c   = k2d[HALF * KS + HALF];
        float inv = 1.0f / sqrtf(c);
        #pragma unroll
        for (int j = 0; j < KS; ++j) cx.g[j] = k2d[j * KS + HALF] * inv;
    }

    // prologue: stage rows 0,1 into pair 0; drain; sync
    stage2(cx, s, 0);
    __syncthreads();

    float4 w[14];
    for (int outer = 0; outer < 4; ++outer) {   // 4*7 = 28 bodies, guard k<22
        body2<0>(outer, cx, s, w);
        body2<1>(outer, cx, s, w);
        body2<2>(outer, cx, s, w);
        body2<3>(outer, cx, s, w);
        body2<4>(outer, cx, s, w);
        body2<5>(outer, cx, s, w);
        body2<6>(outer, cx, s, w);
    }
}

extern "C" void kernel_launch(void* const* d_in, const int* in_sizes, int n_in,
                              void* d_out, int out_size, void* d_ws, size_t ws_size,
                              hipStream_t stream) {
    const float* x   = (const float*)d_in[0];
    const float* k2d = (const float*)d_in[1];
    float*       out = (float*)d_out;

    dim3 grid(IMG_H / TY, 32);   // 32 strips x 32 images = 1024 blocks
    gauss_blur_stream<<<grid, 256, 0, stream>>>(x, k2d, out);
}

// Round 20
// 56.788 us; speedup vs baseline: 1.0292x; 1.0292x over previous
//
#include <hip/hip_runtime.h>

#define KS    13
#define HALF  6
#define TY    32              // output rows per strip (R13 geometry — best measured)
#define NITER (TY + 12)       // 44 staged rows
#define NK    (NITER / 2)     // 22 iterations, 2 rows per barrier pair
#define IMG_H 1024
#define IMG_W 1024

#define GLOBAL_AS __attribute__((address_space(1)))
#define LDS_AS    __attribute__((address_space(3)))

typedef float vfloat4 __attribute__((ext_vector_type(4)));  // native vec for nt-store

__device__ __forceinline__ int reflect_idx(int i, int n) {
    if (i < 0) i = -i;
    if (i >= n) i = 2 * n - 2 - i;
    return i;
}

struct Ctx {
    const float* xin;
    float*       o;
    float        g[KS];
    int          t;        // thread's column granule: cols 4t..4t+3
    int          r0;       // strip's first output row
    bool         interior; // 2 <= t <= 253 : LDS window read needs no column reflect
};

// Stage rows 2k,2k+1 into LDS pair (k&1) via global_load_lds width-16:
// HBM -> LDS direct, no VGPR round-trip, no ds_write. LDS dest is
// wave-uniform base (granule 64w) + lane*16 -- exactly our linear layout.
__device__ __forceinline__ void stage2(const Ctx& cx, float (*s)[IMG_W], int k) {
    const int bp = (k & 1) * 2;
    const int ra = reflect_idx(cx.r0 + 2 * k - 6, IMG_H);
    const int rb = reflect_idx(cx.r0 + 2 * k - 5, IMG_H);
    const float* pa = cx.xin + (size_t)ra * IMG_W + 4 * cx.t;
    const float* pb = cx.xin + (size_t)rb * IMG_W + 4 * cx.t;
    float* la = &s[bp + 0][4 * (cx.t & ~63)];   // wave-uniform
    float* lb = &s[bp + 1][4 * (cx.t & ~63)];
    __builtin_amdgcn_global_load_lds((const GLOBAL_AS void*)pa, (LDS_AS void*)la, 16, 0, 0);
    __builtin_amdgcn_global_load_lds((const GLOBAL_AS void*)pb, (LDS_AS void*)lb, 16, 0, 0);
}

// H-filter one staged row from LDS: 20-float window -> 4 outputs.
__device__ __forceinline__ float4 h_filter(const float* srow, const Ctx& cx) {
    float f[20];
    if (cx.interior) {
        #pragma unroll
        for (int k = 0; k < 5; ++k) {
            float4 v = *reinterpret_cast<const float4*>(srow + 4 * cx.t - 8 + 4 * k);
            f[4*k+0] = v.x; f[4*k+1] = v.y; f[4*k+2] = v.z; f[4*k+3] = v.w;
        }
    } else {
        #pragma unroll
        for (int k = 0; k < 20; ++k)
            f[k] = srow[reflect_idx(4 * cx.t - 8 + k, IMG_W)];
    }
    float4 h = make_float4(0.f, 0.f, 0.f, 0.f);
    #pragma unroll
    for (int j = 0; j < KS; ++j) {
        h.x += cx.g[j] * f[2 + j];
        h.y += cx.g[j] * f[3 + j];
        h.z += cx.g[j] * f[4 + j];
        h.w += cx.g[j] * f[5 + j];
    }
    return h;
}

__device__ __forceinline__ void nt_store4(float* p, const float4& a) {
    vfloat4 v = { a.x, a.y, a.z, a.w };
    __builtin_nontemporal_store(v, reinterpret_cast<vfloat4*>(p));
}

// Iteration k: (1) issue gload_lds for rows 2k+2,2k+3 into the opposite pair;
// (2) B1: s_waitcnt vmcnt(2) -- in-order retire confirms the PAIR-K gloads
//     (issued one iteration ago) landed; the 2 just-issued stay IN FLIGHT --
//     then raw s_barrier so all waves' staging (incl. halo quarters) is visible;
// (3) H-filter rows 2k,2k+1 -> window slots (2U)%14,(2U+1)%14; V -> 2 output
//     rows (nt stores);
// (4) B2: lgkmcnt(0) + raw s_barrier -- all reads of the pair that iteration
//     k+1 will overwrite are complete (WAR).
// NO vmcnt(0) drain anywhere in the loop (T4) -- R19's regression was
// __syncthreads draining the just-issued staging DMAs every iteration.
template<int U>
__device__ __forceinline__ void body2(int outer, const Ctx& cx, float (*s)[IMG_W],
                                      float4 (&w)[14])
{
    const int k = outer * 7 + U;
    if (k >= NK) return;                 // block-uniform guard (barrier-safe)
    const int n0 = 2 * k;
    const int bp = (k & 1) * 2;

    if (k + 1 < NK) stage2(cx, s, k + 1);

    asm volatile("s_waitcnt vmcnt(2)" ::: "memory");
    __builtin_amdgcn_sched_barrier(0);
    __builtin_amdgcn_s_barrier();        // B1: pair-k data landed, all waves
    __builtin_amdgcn_sched_barrier(0);

    // two H-filters into the rolling 14-slot window
    w[(2 * U) % 14]     = h_filter(s[bp + 0], cx);
    w[(2 * U + 1) % 14] = h_filter(s[bp + 1], cx);

    // two V-filters -> output rows r0+n0-12, r0+n0-11
    if (n0 >= 12) {
        float4 a0 = make_float4(0.f, 0.f, 0.f, 0.f);
        float4 a1 = make_float4(0.f, 0.f, 0.f, 0.f);
        #pragma unroll
        for (int j = 0; j < KS; ++j) {
            const float4 v0 = w[(2 * U + 2 + j) % 14];
            const float4 v1 = w[(2 * U + 3 + j) % 14];
            a0.x += cx.g[j] * v0.x;  a1.x += cx.g[j] * v1.x;
            a0.y += cx.g[j] * v0.y;  a1.y += cx.g[j] * v1.y;
            a0.z += cx.g[j] * v0.z;  a1.z += cx.g[j] * v1.z;
            a0.w += cx.g[j] * v0.w;  a1.w += cx.g[j] * v1.w;
        }
        nt_store4(cx.o + (size_t)(cx.r0 + n0 - 12) * IMG_W + 4 * cx.t, a0);
        nt_store4(cx.o + (size_t)(cx.r0 + n0 - 11) * IMG_W + 4 * cx.t, a1);
    }

    asm volatile("s_waitcnt lgkmcnt(0)" ::: "memory");
    __builtin_amdgcn_sched_barrier(0);
    __builtin_amdgcn_s_barrier();        // B2: reads done -> next stage may overwrite
    __builtin_amdgcn_sched_barrier(0);
}

// No launch-bounds min-waves (R2: VGPR cap -> spill). Expect ~90 VGPR.
__global__ __launch_bounds__(256) void gauss_blur_stream(
    const float* __restrict__ x, const float* __restrict__ k2d,
    float* __restrict__ out)
{
    __shared__ float s[4][IMG_W];   // 16384 B: two ping-pong row PAIRS

    Ctx cx;
    cx.t  = threadIdx.x;
    cx.r0 = blockIdx.x * TY;
    const int img = blockIdx.y;
    cx.xin = x + (size_t)img * IMG_H * IMG_W;
    cx.o   = out + (size_t)img * IMG_H * IMG_W;
    cx.interior = (cx.t >= 2) && (cx.t <= 253);

    // 1D taps: k2d = outer(g,g) exactly, g[i] = k2d[i][6]/sqrt(k2d[6][6])
    {
        float c   = k2d[HALF * KS + HALF];
        float inv = 1.0f / sqrtf(c);
        #pragma unroll
        for (int j = 0; j < KS; ++j) cx.g[j] = k2d[j * KS + HALF] * inv;
    }

    // prologue: stage rows 0,1 into pair 0 (body0's vmcnt(2)+B1 completes it)
    stage2(cx, s, 0);

    float4 w[14];
    for (int outer = 0; outer < 4; ++outer) {   // 4*7 = 28 bodies, guard k<22
        body2<0>(outer, cx, s, w);
        body2<1>(outer, cx, s, w);
        body2<2>(outer, cx, s, w);
        body2<3>(outer, cx, s, w);
        body2<4>(outer, cx, s, w);
        body2<5>(outer, cx, s, w);
        body2<6>(outer, cx, s, w);
    }
}

extern "C" void kernel_launch(void* const* d_in, const int* in_sizes, int n_in,
                              void* d_out, int out_size, void* d_ws, size_t ws_size,
                              hipStream_t stream) {
    const float* x   = (const float*)d_in[0];
    const float* k2d = (const float*)d_in[1];
    float*       out = (float*)d_out;

    dim3 grid(IMG_H / TY, 32);   // 32 strips x 32 images = 1024 blocks
    gauss_blur_stream<<<grid, 256, 0, stream>>>(x, k2d, out);
}